// Round 10
// baseline (337.151 us; speedup 1.0000x reference)
//
#include <hip/hip_runtime.h>
#include <hip/hip_bf16.h>
#include <cmath>

#define R_ 64
#define B_ 4096
#define D_ 512
#define C_ 128

typedef __attribute__((ext_vector_type(8))) short bf16x8;
typedef __attribute__((ext_vector_type(4))) float f32x4;

__device__ __forceinline__ unsigned short f2bf(float f) {
  union { float f; unsigned u; } x; x.f = f;
  unsigned r = (x.u + 0x7FFFu + ((x.u >> 16) & 1u)) >> 16;
  return (unsigned short)r;
}

// ---------------- prep: x f32 -> frag-native bf16 ----------------
// xf[mtG 0..255][kc 0..15][lane 0..63][e 0..7]:
//   value = x[mtG*16 + (lane&15)][kc*32 + (lane>>4)*8 + e]
// One wave A-frag (16 rows x 32 k) = contiguous 1 KB.
__global__ __launch_bounds__(256) void prep_xf_kernel(const float* __restrict__ x,
                                                      unsigned short* __restrict__ xf) {
  __shared__ float s[16][516];
  const int mt = blockIdx.x;            // 0..255 global m-tile (16 rows)
  const int t = threadIdx.x;
#pragma unroll
  for (int p = 0; p < 8; ++p) {         // stage 16 rows x 512 f32
    int idx = p * 256 + t;              // 2048 float4
    int row = idx >> 7, c4 = idx & 127;
    float4 v = *reinterpret_cast<const float4*>(&x[(size_t)(mt * 16 + row) * D_ + c4 * 4]);
    *reinterpret_cast<float4*>(&s[row][c4 * 4]) = v;
  }
  __syncthreads();
  const int lane = t & 63, l16 = lane & 15, lhi = lane >> 4;
#pragma unroll
  for (int p = 0; p < 4; ++p) {
    int kc = (t >> 6) + p * 4;          // 0..15
    const float* src = &s[l16][kc * 32 + lhi * 8];
    unsigned short o[8];
#pragma unroll
    for (int e = 0; e < 8; ++e) o[e] = f2bf(src[e]);
    *reinterpret_cast<bf16x8*>(xf + ((size_t)(mt * 16 + kc)) * 512 + lane * 8) =
        *reinterpret_cast<bf16x8*>(o);
  }
}

// ---------------- prep: W f32 -> frag-native bf16 ----------------
// wf[(r*8+nt) 0..511][kc 0..15][lane][e]:
//   value = W[r][kc*32 + (lane>>4)*8 + e][nt*16 + (lane&15)]
// One wave B-frag (16 cols x 32 k) = contiguous 1 KB.
__global__ __launch_bounds__(256) void prep_wf_kernel(const float* __restrict__ W,
                                                      unsigned short* __restrict__ wf) {
  __shared__ float s[32][132];
  const int kc = blockIdx.x;            // 0..15
  const int r = blockIdx.y;             // 0..63
  const int t = threadIdx.x;
#pragma unroll
  for (int p = 0; p < 4; ++p) {         // stage 32 d-rows x 128 c
    int idx = p * 256 + t;              // 1024 float4
    int row = idx >> 5, c4 = idx & 31;
    float4 v = *reinterpret_cast<const float4*>(
        &W[((size_t)r * D_ + kc * 32 + row) * C_ + c4 * 4]);
    *reinterpret_cast<float4*>(&s[row][c4 * 4]) = v;
  }
  __syncthreads();
  const int lane = t & 63, l16 = lane & 15, lhi = lane >> 4;
#pragma unroll
  for (int p = 0; p < 2; ++p) {
    int nt = (t >> 6) + p * 4;          // 0..7
    unsigned short o[8];
#pragma unroll
    for (int e = 0; e < 8; ++e) o[e] = f2bf(s[lhi * 8 + e][nt * 16 + l16]);
    *reinterpret_cast<bf16x8*>(wf + ((size_t)((r * 8 + nt) * 16 + kc)) * 512 + lane * 8) =
        *reinterpret_cast<bf16x8*>(o);
  }
}

// ---------------- prep: (s, -p*s) per (rule, dim) ----------------
__global__ void prep_ps_kernel(const float* __restrict__ proto, const float* __restrict__ var,
                               float* __restrict__ ps) {
  int i = blockIdx.x * 256 + threadIdx.x;          // R*D elements
  float v = fminf(fmaxf(var[i], 1e-4f), 0.1f);
  float s = 1.2011224087864498f / v;
  float2 o; o.x = s; o.y = -proto[i] * s;
  reinterpret_cast<float2*>(ps)[i] = o;
}

// ---------------- antecedent partial: fs_ini accumulation ----------------
__global__ __launch_bounds__(256, 4) void fs_partial_kernel(
    const float* __restrict__ x, const float* __restrict__ ps,
    float* __restrict__ fire) {
  __shared__ float x_s[16 * 68];
  __shared__ __align__(16) float ps_s[64 * 128];   // [rule][dim*2], XOR-swizzled granules
  const int tid = threadIdx.x;
  const int b0 = blockIdx.x * 16;
  const int dq = blockIdx.y;                       // dims dq*64 .. dq*64+63

  {  // stage x tile: 16 rows x 64 dims
    int row = tid >> 4, c4 = tid & 15;
    float4 v = *reinterpret_cast<const float4*>(&x[(size_t)(b0 + row) * D_ + dq * 64 + c4 * 4]);
    *reinterpret_cast<float4*>(&x_s[row * 68 + c4 * 4]) = v;
  }
#pragma unroll
  for (int k = 0; k < 8; ++k) {  // stage ps tile: 64 rules x 32 granules(16B), swizzled
    int g = tid + k * 256;
    int row = g >> 5, gi = g & 31;
    float4 v = *reinterpret_cast<const float4*>(&ps[(size_t)row * (D_ * 2) + dq * 128 + gi * 4]);
    int gs = gi ^ (row & 31);
    *reinterpret_cast<float4*>((char*)ps_s + row * 512 + (gs << 4)) = v;
  }
  __syncthreads();

  const int tr = tid & 63;   // rule = lane
  const int tb = tid >> 6;   // wave -> 4 batch rows
  const int s31 = tr & 31;
  const char* pb = (const char*)ps_s + tr * 512;
  float facc[4] = {0.f, 0.f, 0.f, 0.f};

#pragma unroll
  for (int d4 = 0; d4 < 16; ++d4) {
    float4 psa = *reinterpret_cast<const float4*>(pb + ((((d4 * 2) ^ s31)) << 4));
    float4 psb = *reinterpret_cast<const float4*>(pb + ((((d4 * 2 + 1) ^ s31)) << 4));
#pragma unroll
    for (int i = 0; i < 4; ++i) {
      float4 xv = *reinterpret_cast<const float4*>(&x_s[(tb * 4 + i) * 68 + d4 * 4]);
      float u0 = fmaf(xv.x, psa.x, psa.y);
      float u1 = fmaf(xv.y, psa.z, psa.w);
      float u2 = fmaf(xv.z, psb.x, psb.y);
      float u3 = fmaf(xv.w, psb.z, psb.w);
      facc[i] += exp2f(-(u0 * u0)) + exp2f(-(u1 * u1)) +
                 exp2f(-(u2 * u2)) + exp2f(-(u3 * u3));
    }
  }
#pragma unroll
  for (int i = 0; i < 4; ++i)
    atomicAdd(&fire[(size_t)(b0 + tb * 4 + i) * R_ + tr], facc[i]);
}

// ---------------- softmax over rules, in place on fire buffer ----------------
__global__ void softmax_kernel(float* __restrict__ fire) {
  const int b = blockIdx.x * 4 + (threadIdx.x >> 6);
  const int r = threadIdx.x & 63;
  float v = fire[(size_t)b * R_ + r];
  float m = v;
#pragma unroll
  for (int off = 32; off; off >>= 1) m = fmaxf(m, __shfl_xor(m, off, 64));
  float e = exp2f((v - m) * 1.4426950408889634f);
  float s = e;
#pragma unroll
  for (int off = 32; off; off >>= 1) s += __shfl_xor(s, off, 64);
  fire[(size_t)b * R_ + r] = e / s;
}

// ---------------- fused rule-GEMM: LDS-free, barrier-free ----------------
// Operands pre-packed in frag-native layout; each frag load = contiguous 1 KB
// global_load_dwordx4 (L2-resident). BM=128, 4 waves 2x2, wave 64x64,
// 4 rules/block, grid (32 bm, 16 rg) = 512 blocks = 2/CU. Frag dbuf over kc,
// fully unrolled (static indexing). No LDS, no barriers, no vmcnt drains.
__global__ __launch_bounds__(256, 2) void gemm_kernel(
    const unsigned short* __restrict__ xf, const unsigned short* __restrict__ wf,
    const float* __restrict__ fire, const float* __restrict__ bias,
    float* __restrict__ out) {
  const int tid = threadIdx.x;
  const int bm = blockIdx.x;   // 0..31 batch block (128 rows)
  const int rg = blockIdx.y;   // 0..15 rule group (4 rules)
  const int b0 = bm * 128;

  const int wid = tid >> 6, lane = tid & 63;
  const int wm = wid >> 1, wn = wid & 1;           // 2x2 wave grid, wave tile 64x64
  const int l16 = lane & 15, lhi = lane >> 4;

  // A-frag bases: 4 m-tiles of this wave
  const unsigned short* abase[4];
#pragma unroll
  for (int m = 0; m < 4; ++m)
    abase[m] = xf + ((size_t)((bm * 8 + wm * 4 + m) * 16)) * 512 + lane * 8;

  // bias hoist: 4 rules x 4 n-tiles
  float bias_r[4][4];
#pragma unroll
  for (int g = 0; g < 4; ++g)
#pragma unroll
    for (int n = 0; n < 4; ++n)
      bias_r[g][n] = bias[(rg * 4 + g) * C_ + wn * 64 + n * 16 + l16];

  float tot[4][4][4];
#pragma unroll
  for (int m = 0; m < 4; ++m)
#pragma unroll
    for (int n = 0; n < 4; ++n)
#pragma unroll
      for (int j = 0; j < 4; ++j) tot[m][n][j] = 0.f;

  for (int g = 0; g < 4; ++g) {
    const unsigned short* bbase[4];
#pragma unroll
    for (int n = 0; n < 4; ++n)
      bbase[n] = wf + ((size_t)(((rg * 4 + g) * 8 + wn * 4 + n) * 16)) * 512 + lane * 8;

    f32x4 acc[4][4];
#pragma unroll
    for (int m = 0; m < 4; ++m)
#pragma unroll
      for (int n = 0; n < 4; ++n)
        acc[m][n] = f32x4{0.f, 0.f, 0.f, 0.f};

    bf16x8 av[2][4], bv[2][4];
#pragma unroll
    for (int m = 0; m < 4; ++m) av[0][m] = *reinterpret_cast<const bf16x8*>(abase[m]);
#pragma unroll
    for (int n = 0; n < 4; ++n) bv[0][n] = *reinterpret_cast<const bf16x8*>(bbase[n]);

#pragma unroll
    for (int kc = 0; kc < 16; ++kc) {
      const int cur = kc & 1, nxt = cur ^ 1;
      if (kc < 15) {   // prefetch next chunk's frags (dbuf; unrolled -> static)
#pragma unroll
        for (int m = 0; m < 4; ++m)
          av[nxt][m] = *reinterpret_cast<const bf16x8*>(abase[m] + (kc + 1) * 512);
#pragma unroll
        for (int n = 0; n < 4; ++n)
          bv[nxt][n] = *reinterpret_cast<const bf16x8*>(bbase[n] + (kc + 1) * 512);
      }
#pragma unroll
      for (int m = 0; m < 4; ++m)
#pragma unroll
        for (int n = 0; n < 4; ++n)
          acc[m][n] = __builtin_amdgcn_mfma_f32_16x16x32_bf16(av[cur][m], bv[cur][n], acc[m][n], 0, 0, 0);
    }

    // rule epilogue: relu(+bias) * fire, accumulate into tot
#pragma unroll
    for (int m = 0; m < 4; ++m) {
      float fire_v[4];
#pragma unroll
      for (int j = 0; j < 4; ++j)
        fire_v[j] = fire[(size_t)(b0 + wm * 64 + m * 16 + lhi * 4 + j) * R_ + rg * 4 + g];
#pragma unroll
      for (int n = 0; n < 4; ++n)
#pragma unroll
        for (int j = 0; j < 4; ++j) {
          float v = acc[m][n][j] + bias_r[g][n];
          v = fmaxf(v, 0.f);
          tot[m][n][j] += v * fire_v[j];
        }
    }
  }

#pragma unroll
  for (int m = 0; m < 4; ++m)
#pragma unroll
    for (int n = 0; n < 4; ++n) {
      int col = wn * 64 + n * 16 + l16;
#pragma unroll
      for (int j = 0; j < 4; ++j) {
        int rowl = wm * 64 + m * 16 + lhi * 4 + j;
        atomicAdd(&out[(size_t)(b0 + rowl) * C_ + col], tot[m][n][j]);
      }
    }
}

extern "C" void kernel_launch(void* const* d_in, const int* in_sizes, int n_in,
                              void* d_out, int out_size, void* d_ws, size_t ws_size,
                              hipStream_t stream) {
  const float* x     = (const float*)d_in[0];
  const float* proto = (const float*)d_in[1];
  const float* var   = (const float*)d_in[2];
  const float* W     = (const float*)d_in[3];
  const float* bias  = (const float*)d_in[4];
  float* out  = (float*)d_out;
  float* fire = out + (size_t)B_ * C_;   // second output region (also fs_ini accumulator)

  const size_t WS_XF = (size_t)B_ * D_ * sizeof(unsigned short);       // 4 MiB frag-x
  const size_t WS_WF = (size_t)R_ * C_ * D_ * sizeof(unsigned short);  // 8 MiB frag-W
  const size_t WS_PS = (size_t)R_ * D_ * 2 * sizeof(float);            // 256 KiB
  if (ws_size < WS_XF + WS_WF + WS_PS) return;  // insufficient scratch -> visible failure

  unsigned short* xf = (unsigned short*)d_ws;
  unsigned short* wfp = (unsigned short*)((char*)d_ws + WS_XF);
  float*          ps  = (float*)((char*)d_ws + WS_XF + WS_WF);

  // zero BOTH output regions: out accumulates gemm atomics, fire accumulates fs partials
  hipMemsetAsync(d_out, 0, (size_t)out_size * sizeof(float), stream);
  prep_xf_kernel<<<dim3(B_ / 16), dim3(256), 0, stream>>>(x, xf);
  prep_wf_kernel<<<dim3(16, 64), dim3(256), 0, stream>>>(W, wfp);
  prep_ps_kernel<<<dim3(R_ * D_ / 256), dim3(256), 0, stream>>>(proto, var, ps);
  fs_partial_kernel<<<dim3(B_ / 16, 8), dim3(256), 0, stream>>>(x, ps, fire);
  softmax_kernel<<<dim3(B_ / 4), dim3(256), 0, stream>>>(fire);
  gemm_kernel<<<dim3(B_ / 128, R_ / 4), dim3(256), 0, stream>>>(xf, wfp, fire, bias, out);
}

// Round 11
// 181.285 us; speedup vs baseline: 1.8598x; 1.8598x over previous
//
#include <hip/hip_runtime.h>
#include <hip/hip_bf16.h>
#include <cmath>

#define R_ 64
#define B_ 4096
#define D_ 512
#define C_ 128

typedef __attribute__((ext_vector_type(8))) short bf16x8;
typedef __attribute__((ext_vector_type(4))) float f32x4;

__device__ __forceinline__ unsigned short f2bf(float f) {
  union { float f; unsigned u; } x; x.f = f;
  unsigned r = (x.u + 0x7FFFu + ((x.u >> 16) & 1u)) >> 16;
  return (unsigned short)r;
}

// ---------------- prep: x f32 -> frag-native bf16 ----------------
// xf[mtG 0..255][kc 0..15][lane 0..63][e 0..7]:
//   value = x[mtG*16 + (lane&15)][kc*32 + (lane>>4)*8 + e]
// One wave A-frag (16 rows x 32 k) = contiguous 1 KB.
__global__ __launch_bounds__(256) void prep_xf_kernel(const float* __restrict__ x,
                                                      unsigned short* __restrict__ xf) {
  __shared__ float s[16][516];
  const int mt = blockIdx.x;            // 0..255 global m-tile (16 rows)
  const int t = threadIdx.x;
#pragma unroll
  for (int p = 0; p < 8; ++p) {         // stage 16 rows x 512 f32
    int idx = p * 256 + t;              // 2048 float4
    int row = idx >> 7, c4 = idx & 127;
    float4 v = *reinterpret_cast<const float4*>(&x[(size_t)(mt * 16 + row) * D_ + c4 * 4]);
    *reinterpret_cast<float4*>(&s[row][c4 * 4]) = v;
  }
  __syncthreads();
  const int lane = t & 63, l16 = lane & 15, lhi = lane >> 4;
#pragma unroll
  for (int p = 0; p < 4; ++p) {
    int kc = (t >> 6) + p * 4;          // 0..15
    const float* src = &s[l16][kc * 32 + lhi * 8];
    unsigned short o[8];
#pragma unroll
    for (int e = 0; e < 8; ++e) o[e] = f2bf(src[e]);
    *reinterpret_cast<bf16x8*>(xf + ((size_t)(mt * 16 + kc)) * 512 + lane * 8) =
        *reinterpret_cast<bf16x8*>(o);
  }
}

// ---------------- prep: W f32 -> frag-native bf16 ----------------
// wf[(r*8+nt) 0..511][kc 0..15][lane][e]:
//   value = W[r][kc*32 + (lane>>4)*8 + e][nt*16 + (lane&15)]
// One wave B-frag (16 cols x 32 k) = contiguous 1 KB.
__global__ __launch_bounds__(256) void prep_wf_kernel(const float* __restrict__ W,
                                                      unsigned short* __restrict__ wf) {
  __shared__ float s[32][132];
  const int kc = blockIdx.x;            // 0..15
  const int r = blockIdx.y;             // 0..63
  const int t = threadIdx.x;
#pragma unroll
  for (int p = 0; p < 4; ++p) {         // stage 32 d-rows x 128 c
    int idx = p * 256 + t;              // 1024 float4
    int row = idx >> 5, c4 = idx & 31;
    float4 v = *reinterpret_cast<const float4*>(
        &W[((size_t)r * D_ + kc * 32 + row) * C_ + c4 * 4]);
    *reinterpret_cast<float4*>(&s[row][c4 * 4]) = v;
  }
  __syncthreads();
  const int lane = t & 63, l16 = lane & 15, lhi = lane >> 4;
#pragma unroll
  for (int p = 0; p < 2; ++p) {
    int nt = (t >> 6) + p * 4;          // 0..7
    unsigned short o[8];
#pragma unroll
    for (int e = 0; e < 8; ++e) o[e] = f2bf(s[lhi * 8 + e][nt * 16 + l16]);
    *reinterpret_cast<bf16x8*>(wf + ((size_t)((r * 8 + nt) * 16 + kc)) * 512 + lane * 8) =
        *reinterpret_cast<bf16x8*>(o);
  }
}

// ---------------- prep: (s, -p*s) per (rule, dim) ----------------
__global__ void prep_ps_kernel(const float* __restrict__ proto, const float* __restrict__ var,
                               float* __restrict__ ps) {
  int i = blockIdx.x * 256 + threadIdx.x;          // R*D elements
  float v = fminf(fmaxf(var[i], 1e-4f), 0.1f);
  float s = 1.2011224087864498f / v;
  float2 o; o.x = s; o.y = -proto[i] * s;
  reinterpret_cast<float2*>(ps)[i] = o;
}

// ---------------- antecedent partial: fs_ini accumulation ----------------
__global__ __launch_bounds__(256, 4) void fs_partial_kernel(
    const float* __restrict__ x, const float* __restrict__ ps,
    float* __restrict__ fire) {
  __shared__ float x_s[16 * 68];
  __shared__ __align__(16) float ps_s[64 * 128];   // [rule][dim*2], XOR-swizzled granules
  const int tid = threadIdx.x;
  const int b0 = blockIdx.x * 16;
  const int dq = blockIdx.y;                       // dims dq*64 .. dq*64+63

  {  // stage x tile: 16 rows x 64 dims
    int row = tid >> 4, c4 = tid & 15;
    float4 v = *reinterpret_cast<const float4*>(&x[(size_t)(b0 + row) * D_ + dq * 64 + c4 * 4]);
    *reinterpret_cast<float4*>(&x_s[row * 68 + c4 * 4]) = v;
  }
#pragma unroll
  for (int k = 0; k < 8; ++k) {  // stage ps tile: 64 rules x 32 granules(16B), swizzled
    int g = tid + k * 256;
    int row = g >> 5, gi = g & 31;
    float4 v = *reinterpret_cast<const float4*>(&ps[(size_t)row * (D_ * 2) + dq * 128 + gi * 4]);
    int gs = gi ^ (row & 31);
    *reinterpret_cast<float4*>((char*)ps_s + row * 512 + (gs << 4)) = v;
  }
  __syncthreads();

  const int tr = tid & 63;   // rule = lane
  const int tb = tid >> 6;   // wave -> 4 batch rows
  const int s31 = tr & 31;
  const char* pb = (const char*)ps_s + tr * 512;
  float facc[4] = {0.f, 0.f, 0.f, 0.f};

#pragma unroll
  for (int d4 = 0; d4 < 16; ++d4) {
    float4 psa = *reinterpret_cast<const float4*>(pb + ((((d4 * 2) ^ s31)) << 4));
    float4 psb = *reinterpret_cast<const float4*>(pb + ((((d4 * 2 + 1) ^ s31)) << 4));
#pragma unroll
    for (int i = 0; i < 4; ++i) {
      float4 xv = *reinterpret_cast<const float4*>(&x_s[(tb * 4 + i) * 68 + d4 * 4]);
      float u0 = fmaf(xv.x, psa.x, psa.y);
      float u1 = fmaf(xv.y, psa.z, psa.w);
      float u2 = fmaf(xv.z, psb.x, psb.y);
      float u3 = fmaf(xv.w, psb.z, psb.w);
      facc[i] += exp2f(-(u0 * u0)) + exp2f(-(u1 * u1)) +
                 exp2f(-(u2 * u2)) + exp2f(-(u3 * u3));
    }
  }
#pragma unroll
  for (int i = 0; i < 4; ++i)
    atomicAdd(&fire[(size_t)(b0 + tb * 4 + i) * R_ + tr], facc[i]);
}

// ---------------- softmax over rules, in place on fire buffer ----------------
__global__ void softmax_kernel(float* __restrict__ fire) {
  const int b = blockIdx.x * 4 + (threadIdx.x >> 6);
  const int r = threadIdx.x & 63;
  float v = fire[(size_t)b * R_ + r];
  float m = v;
#pragma unroll
  for (int off = 32; off; off >>= 1) m = fmaxf(m, __shfl_xor(m, off, 64));
  float e = exp2f((v - m) * 1.4426950408889634f);
  float s = e;
#pragma unroll
  for (int off = 32; off; off >>= 1) s += __shfl_xor(s, off, 64);
  fire[(size_t)b * R_ + r] = e / s;
}

// ---------------- fused rule-GEMM: LDS-free, barrier-free ----------------
// Operands pre-packed in frag-native layout; each frag load = contiguous 1 KB
// global_load_dwordx4 (L2/L3-resident). BM=128, 4 waves 2x2, wave 64x64,
// 4 rules/block, grid (32 bm, 16 rg). Frag dbuf over kc, fully unrolled.
// No LDS, no barriers. NOTE: no min-occupancy cap — ~240 live VGPRs; the
// (256,2) cap in R10 forced 128 VGPRs and spilled 900 MB to scratch.
__global__ __launch_bounds__(256) void gemm_kernel(
    const unsigned short* __restrict__ xf, const unsigned short* __restrict__ wf,
    const float* __restrict__ fire, const float* __restrict__ bias,
    float* __restrict__ out) {
  const int tid = threadIdx.x;
  const int bm = blockIdx.x;   // 0..31 batch block (128 rows)
  const int rg = blockIdx.y;   // 0..15 rule group (4 rules)
  const int b0 = bm * 128;

  const int wid = tid >> 6, lane = tid & 63;
  const int wm = wid >> 1, wn = wid & 1;           // 2x2 wave grid, wave tile 64x64
  const int l16 = lane & 15, lhi = lane >> 4;

  // A-frag bases: 4 m-tiles of this wave
  const unsigned short* abase[4];
#pragma unroll
  for (int m = 0; m < 4; ++m)
    abase[m] = xf + ((size_t)((bm * 8 + wm * 4 + m) * 16)) * 512 + lane * 8;

  // bias hoist: 4 rules x 4 n-tiles
  float bias_r[4][4];
#pragma unroll
  for (int g = 0; g < 4; ++g)
#pragma unroll
    for (int n = 0; n < 4; ++n)
      bias_r[g][n] = bias[(rg * 4 + g) * C_ + wn * 64 + n * 16 + l16];

  float tot[4][4][4];
#pragma unroll
  for (int m = 0; m < 4; ++m)
#pragma unroll
    for (int n = 0; n < 4; ++n)
#pragma unroll
      for (int j = 0; j < 4; ++j) tot[m][n][j] = 0.f;

  for (int g = 0; g < 4; ++g) {
    const unsigned short* bbase[4];
#pragma unroll
    for (int n = 0; n < 4; ++n)
      bbase[n] = wf + ((size_t)(((rg * 4 + g) * 8 + wn * 4 + n) * 16)) * 512 + lane * 8;

    f32x4 acc[4][4];
#pragma unroll
    for (int m = 0; m < 4; ++m)
#pragma unroll
      for (int n = 0; n < 4; ++n)
        acc[m][n] = f32x4{0.f, 0.f, 0.f, 0.f};

    bf16x8 av[2][4], bv[2][4];
#pragma unroll
    for (int m = 0; m < 4; ++m) av[0][m] = *reinterpret_cast<const bf16x8*>(abase[m]);
#pragma unroll
    for (int n = 0; n < 4; ++n) bv[0][n] = *reinterpret_cast<const bf16x8*>(bbase[n]);

#pragma unroll
    for (int kc = 0; kc < 16; ++kc) {
      const int cur = kc & 1, nxt = cur ^ 1;
      if (kc < 15) {   // prefetch next chunk's frags (dbuf; unrolled -> static)
#pragma unroll
        for (int m = 0; m < 4; ++m)
          av[nxt][m] = *reinterpret_cast<const bf16x8*>(abase[m] + (kc + 1) * 512);
#pragma unroll
        for (int n = 0; n < 4; ++n)
          bv[nxt][n] = *reinterpret_cast<const bf16x8*>(bbase[n] + (kc + 1) * 512);
      }
#pragma unroll
      for (int m = 0; m < 4; ++m)
#pragma unroll
        for (int n = 0; n < 4; ++n)
          acc[m][n] = __builtin_amdgcn_mfma_f32_16x16x32_bf16(av[cur][m], bv[cur][n], acc[m][n], 0, 0, 0);
    }

    // rule epilogue: relu(+bias) * fire, accumulate into tot
#pragma unroll
    for (int m = 0; m < 4; ++m) {
      float fire_v[4];
#pragma unroll
      for (int j = 0; j < 4; ++j)
        fire_v[j] = fire[(size_t)(b0 + wm * 64 + m * 16 + lhi * 4 + j) * R_ + rg * 4 + g];
#pragma unroll
      for (int n = 0; n < 4; ++n)
#pragma unroll
        for (int j = 0; j < 4; ++j) {
          float v = acc[m][n][j] + bias_r[g][n];
          v = fmaxf(v, 0.f);
          tot[m][n][j] += v * fire_v[j];
        }
    }
  }

#pragma unroll
  for (int m = 0; m < 4; ++m)
#pragma unroll
    for (int n = 0; n < 4; ++n) {
      int col = wn * 64 + n * 16 + l16;
#pragma unroll
      for (int j = 0; j < 4; ++j) {
        int rowl = wm * 64 + m * 16 + lhi * 4 + j;
        atomicAdd(&out[(size_t)(b0 + rowl) * C_ + col], tot[m][n][j]);
      }
    }
}

extern "C" void kernel_launch(void* const* d_in, const int* in_sizes, int n_in,
                              void* d_out, int out_size, void* d_ws, size_t ws_size,
                              hipStream_t stream) {
  const float* x     = (const float*)d_in[0];
  const float* proto = (const float*)d_in[1];
  const float* var   = (const float*)d_in[2];
  const float* W     = (const float*)d_in[3];
  const float* bias  = (const float*)d_in[4];
  float* out  = (float*)d_out;
  float* fire = out + (size_t)B_ * C_;   // second output region (also fs_ini accumulator)

  const size_t WS_XF = (size_t)B_ * D_ * sizeof(unsigned short);       // 4 MiB frag-x
  const size_t WS_WF = (size_t)R_ * C_ * D_ * sizeof(unsigned short);  // 8 MiB frag-W
  const size_t WS_PS = (size_t)R_ * D_ * 2 * sizeof(float);            // 256 KiB
  if (ws_size < WS_XF + WS_WF + WS_PS) return;  // insufficient scratch -> visible failure

  unsigned short* xf = (unsigned short*)d_ws;
  unsigned short* wfp = (unsigned short*)((char*)d_ws + WS_XF);
  float*          ps  = (float*)((char*)d_ws + WS_XF + WS_WF);

  // zero BOTH output regions: out accumulates gemm atomics, fire accumulates fs partials
  hipMemsetAsync(d_out, 0, (size_t)out_size * sizeof(float), stream);
  prep_xf_kernel<<<dim3(B_ / 16), dim3(256), 0, stream>>>(x, xf);
  prep_wf_kernel<<<dim3(16, 64), dim3(256), 0, stream>>>(W, wfp);
  prep_ps_kernel<<<dim3(R_ * D_ / 256), dim3(256), 0, stream>>>(proto, var, ps);
  fs_partial_kernel<<<dim3(B_ / 16, 8), dim3(256), 0, stream>>>(x, ps, fire);
  softmax_kernel<<<dim3(B_ / 4), dim3(256), 0, stream>>>(fire);
  gemm_kernel<<<dim3(B_ / 128, R_ / 4), dim3(256), 0, stream>>>(xf, wfp, fire, bias, out);
}

// Round 12
// 122.743 us; speedup vs baseline: 2.7468x; 1.4769x over previous
//
#include <hip/hip_runtime.h>
#include <hip/hip_bf16.h>
#include <cmath>

#define R_ 64
#define B_ 4096
#define D_ 512
#define C_ 128

typedef __attribute__((ext_vector_type(8))) short bf16x8;
typedef __attribute__((ext_vector_type(4))) float f32x4;

__device__ __forceinline__ unsigned short f2bf(float f) {
  union { float f; unsigned u; } x; x.f = f;
  unsigned r = (x.u + 0x7FFFu + ((x.u >> 16) & 1u)) >> 16;
  return (unsigned short)r;
}

// ---------------- prep: x f32 -> bf16 ----------------
__global__ void prep_x_kernel(const float* __restrict__ x, unsigned short* __restrict__ xw) {
  int i = blockIdx.x * 256 + threadIdx.x;          // float4 index, exact count
  float4 v = reinterpret_cast<const float4*>(x)[i];
  ushort4 o;
  o.x = f2bf(v.x); o.y = f2bf(v.y); o.z = f2bf(v.z); o.w = f2bf(v.w);
  reinterpret_cast<ushort4*>(xw)[i] = o;
}

// ---------------- prep: W[r][d][c] f32 -> W^T[r][c][d] bf16 ----------------
__global__ void prep_w_kernel(const float* __restrict__ W, unsigned short* __restrict__ wt) {
  __shared__ float t[32][33];
  int bx = blockIdx.x;
  int r = bx >> 6;
  int rem = bx & 63;
  int d0 = (rem >> 2) << 5;   // 16 d-tiles of 32
  int c0 = (rem & 3) << 5;    // 4 c-tiles of 32
  int tx = threadIdx.x & 31, ty = threadIdx.x >> 5;  // 32 x 8
  const float* Wr = W + (size_t)r * D_ * C_;
#pragma unroll
  for (int q = 0; q < 4; ++q) {
    int dl = q * 8 + ty;
    t[dl][tx] = Wr[(size_t)(d0 + dl) * C_ + c0 + tx];
  }
  __syncthreads();
  unsigned short* wtr = wt + (size_t)r * C_ * D_;
#pragma unroll
  for (int q = 0; q < 4; ++q) {
    int cl = q * 8 + ty;
    float v = t[tx][cl];                         // transposed read, pad-33 conflict-free
    wtr[(size_t)(c0 + cl) * D_ + d0 + tx] = f2bf(v);
  }
}

// ---------------- prep: (s, -p*s) per (rule, dim) ----------------
__global__ void prep_ps_kernel(const float* __restrict__ proto, const float* __restrict__ var,
                               float* __restrict__ ps) {
  int i = blockIdx.x * 256 + threadIdx.x;          // R*D elements
  float v = fminf(fmaxf(var[i], 1e-4f), 0.1f);
  float s = 1.2011224087864498f / v;
  float2 o; o.x = s; o.y = -proto[i] * s;
  reinterpret_cast<float2*>(ps)[i] = o;
}

// ---------------- antecedent partial: fs_ini accumulation ----------------
__global__ __launch_bounds__(256, 4) void fs_partial_kernel(
    const float* __restrict__ x, const float* __restrict__ ps,
    float* __restrict__ fire) {
  __shared__ float x_s[16 * 68];
  __shared__ __align__(16) float ps_s[64 * 128];   // [rule][dim*2], XOR-swizzled granules
  const int tid = threadIdx.x;
  const int b0 = blockIdx.x * 16;
  const int dq = blockIdx.y;                       // dims dq*64 .. dq*64+63

  {  // stage x tile: 16 rows x 64 dims
    int row = tid >> 4, c4 = tid & 15;
    float4 v = *reinterpret_cast<const float4*>(&x[(size_t)(b0 + row) * D_ + dq * 64 + c4 * 4]);
    *reinterpret_cast<float4*>(&x_s[row * 68 + c4 * 4]) = v;
  }
#pragma unroll
  for (int k = 0; k < 8; ++k) {  // stage ps tile: 64 rules x 32 granules(16B), swizzled
    int g = tid + k * 256;
    int row = g >> 5, gi = g & 31;
    float4 v = *reinterpret_cast<const float4*>(&ps[(size_t)row * (D_ * 2) + dq * 128 + gi * 4]);
    int gs = gi ^ (row & 31);
    *reinterpret_cast<float4*>((char*)ps_s + row * 512 + (gs << 4)) = v;
  }
  __syncthreads();

  const int tr = tid & 63;   // rule = lane
  const int tb = tid >> 6;   // wave -> 4 batch rows
  const int s31 = tr & 31;
  const char* pb = (const char*)ps_s + tr * 512;
  float facc[4] = {0.f, 0.f, 0.f, 0.f};

#pragma unroll
  for (int d4 = 0; d4 < 16; ++d4) {
    float4 psa = *reinterpret_cast<const float4*>(pb + ((((d4 * 2) ^ s31)) << 4));
    float4 psb = *reinterpret_cast<const float4*>(pb + ((((d4 * 2 + 1) ^ s31)) << 4));
#pragma unroll
    for (int i = 0; i < 4; ++i) {
      float4 xv = *reinterpret_cast<const float4*>(&x_s[(tb * 4 + i) * 68 + d4 * 4]);
      float u0 = fmaf(xv.x, psa.x, psa.y);
      float u1 = fmaf(xv.y, psa.z, psa.w);
      float u2 = fmaf(xv.z, psb.x, psb.y);
      float u3 = fmaf(xv.w, psb.z, psb.w);
      facc[i] += exp2f(-(u0 * u0)) + exp2f(-(u1 * u1)) +
                 exp2f(-(u2 * u2)) + exp2f(-(u3 * u3));
    }
  }
#pragma unroll
  for (int i = 0; i < 4; ++i)
    atomicAdd(&fire[(size_t)(b0 + tb * 4 + i) * R_ + tr], facc[i]);
}

// ---------------- softmax over rules, in place on fire buffer ----------------
__global__ void softmax_kernel(float* __restrict__ fire) {
  const int b = blockIdx.x * 4 + (threadIdx.x >> 6);
  const int r = threadIdx.x & 63;
  float v = fire[(size_t)b * R_ + r];
  float m = v;
#pragma unroll
  for (int off = 32; off; off >>= 1) m = fmaxf(m, __shfl_xor(m, off, 64));
  float e = exp2f((v - m) * 1.4426950408889634f);
  float s = e;
#pragma unroll
  for (int off = 32; off; off >>= 1) s += __shfl_xor(s, off, 64);
  fire[(size_t)b * R_ + r] = e / s;
}

// ---------------- fused rule-GEMM + relu + fire-weighted combine ----------------
// R3 body (79 us measured) + XCD-aware swizzle: 1D grid, flat f ->
// xcd k = f&7 owns rule-groups {2k, 2k+1}; per-XCD W working set = 1 MB
// (fits 4 MB L2) instead of all 8 MB thrashing every XCD's L2.
// BM=128, BN=C=128, BK=64. 4 waves (2x2), wave tile 64x64. 4 rules/block.
__global__ __launch_bounds__(256, 2) void gemm_kernel(
    const unsigned short* __restrict__ xw, const unsigned short* __restrict__ wt,
    const float* __restrict__ fire, const float* __restrict__ bias,
    float* __restrict__ out) {
  __shared__ __align__(16) unsigned short x_s[2][128 * 64];
  __shared__ __align__(16) unsigned short w_s[2][128 * 64];
  __shared__ float fire_s[128 * 4];
  __shared__ float bias_s[4 * 128];

  const int tid = threadIdx.x;
  // XCD-aware decode: xcd = f&7 gets rgs {2*xcd, 2*xcd+1}, all 32 bms each
  const int f = blockIdx.x;          // 0..511
  const int xcd = f & 7;
  const int idx = f >> 3;            // 0..63
  const int rg = 2 * xcd + (idx & 1);
  const int bm = idx >> 1;           // 0..31
  const int b0 = bm * 128;

  {
    for (int t = tid; t < 512; t += 256) {
      int row = t >> 2, g = t & 3;
      fire_s[t] = fire[(size_t)(b0 + row) * R_ + rg * 4 + g];
    }
    for (int t = tid; t < 512; t += 256) {
      bias_s[t] = bias[rg * 4 * C_ + t];
    }
  }

  const int wid = tid >> 6, lane = tid & 63;
  const int wm = wid >> 1, wn = wid & 1;           // 2 x 2 wave grid, wave tile 64x64
  const int l16 = lane & 15, lhi = lane >> 4;

  // ds_read byte offsets (XOR-swizzled 16B granules within 128B rows)
  int offA[4][2], offB[4][2];
#pragma unroll
  for (int m = 0; m < 4; ++m) {
    int row = wm * 64 + m * 16 + l16;
#pragma unroll
    for (int ks = 0; ks < 2; ++ks)
      offA[m][ks] = row * 128 + (((ks * 4 + lhi) ^ (row & 7)) << 4);
  }
#pragma unroll
  for (int n = 0; n < 4; ++n) {
    int row = wn * 64 + n * 16 + l16;
#pragma unroll
    for (int ks = 0; ks < 2; ++ks)
      offB[n][ks] = row * 128 + (((ks * 4 + lhi) ^ (row & 7)) << 4);
  }

  const unsigned short* xsrc = xw + (size_t)b0 * D_;
  const unsigned short* wbase = wt + (size_t)(rg * 4) * C_ * D_;

  float tot[4][4][4];
#pragma unroll
  for (int m = 0; m < 4; ++m)
#pragma unroll
    for (int n = 0; n < 4; ++n)
#pragma unroll
      for (int j = 0; j < 4; ++j) tot[m][n][j] = 0.f;

  f32x4 acc[4][4];

  // stage one 128x64 bf16 tile: linear LDS dest, inverse-swizzled global source
  auto stage = [&](unsigned short* lds, const unsigned short* src, int kc) {
#pragma unroll
    for (int q = 0; q < 4; ++q) {
      int ch = q * 256 + tid;          // 1024 x 16B chunks
      int row = ch >> 3, g = ch & 7;
      const unsigned short* ga = src + (size_t)row * D_ + kc + ((g ^ (row & 7)) << 3);
      __builtin_amdgcn_global_load_lds(
          (const __attribute__((address_space(1))) void*)ga,
          (__attribute__((address_space(3))) void*)(lds + ch * 8), 16, 0, 0);
    }
  };

  stage(x_s[0], xsrc, 0);
  stage(w_s[0], wbase, 0);
  asm volatile("s_waitcnt vmcnt(0)" ::: "memory");
  __syncthreads();

  int cur = 0;
  for (int s = 0; s < 32; ++s) {
    const int g = s >> 3, kk = s & 7;
    if (kk == 0) {
#pragma unroll
      for (int m = 0; m < 4; ++m)
#pragma unroll
        for (int n = 0; n < 4; ++n)
          acc[m][n] = f32x4{0.f, 0.f, 0.f, 0.f};
    }
    if (s + 1 < 32) {
      const int s1 = s + 1;
      stage(x_s[cur ^ 1], xsrc, (s1 & 7) * 64);
      stage(w_s[cur ^ 1], wbase + (size_t)(s1 >> 3) * C_ * D_, (s1 & 7) * 64);
    }
    const char* xb = (const char*)x_s[cur];
    const char* wb = (const char*)w_s[cur];
    bf16x8 av[4][2], bv[4][2];
#pragma unroll
    for (int m = 0; m < 4; ++m)
#pragma unroll
      for (int ks = 0; ks < 2; ++ks)
        av[m][ks] = *reinterpret_cast<const bf16x8*>(xb + offA[m][ks]);
#pragma unroll
    for (int n = 0; n < 4; ++n)
#pragma unroll
      for (int ks = 0; ks < 2; ++ks)
        bv[n][ks] = *reinterpret_cast<const bf16x8*>(wb + offB[n][ks]);
#pragma unroll
    for (int ks = 0; ks < 2; ++ks)
#pragma unroll
      for (int m = 0; m < 4; ++m)
#pragma unroll
        for (int n = 0; n < 4; ++n)
          acc[m][n] = __builtin_amdgcn_mfma_f32_16x16x32_bf16(av[m][ks], bv[n][ks], acc[m][n], 0, 0, 0);
    if (kk == 7) {  // rule g finished: relu(+bias) * fire, accumulate
#pragma unroll
      for (int m = 0; m < 4; ++m)
#pragma unroll
        for (int n = 0; n < 4; ++n) {
          int col = wn * 64 + n * 16 + l16;
          float bi = bias_s[g * 128 + col];
#pragma unroll
          for (int j = 0; j < 4; ++j) {
            int rowl = wm * 64 + m * 16 + lhi * 4 + j;
            float v = acc[m][n][j] + bi;
            v = fmaxf(v, 0.f);
            tot[m][n][j] += v * fire_s[rowl * 4 + g];
          }
        }
    }
    asm volatile("s_waitcnt vmcnt(0)" ::: "memory");
    __syncthreads();
    cur ^= 1;
  }

#pragma unroll
  for (int m = 0; m < 4; ++m)
#pragma unroll
    for (int n = 0; n < 4; ++n) {
      int col = wn * 64 + n * 16 + l16;
#pragma unroll
      for (int j = 0; j < 4; ++j) {
        int rowl = wm * 64 + m * 16 + lhi * 4 + j;
        atomicAdd(&out[(size_t)(b0 + rowl) * C_ + col], tot[m][n][j]);
      }
    }
}

extern "C" void kernel_launch(void* const* d_in, const int* in_sizes, int n_in,
                              void* d_out, int out_size, void* d_ws, size_t ws_size,
                              hipStream_t stream) {
  const float* x     = (const float*)d_in[0];
  const float* proto = (const float*)d_in[1];
  const float* var   = (const float*)d_in[2];
  const float* W     = (const float*)d_in[3];
  const float* bias  = (const float*)d_in[4];
  float* out  = (float*)d_out;
  float* fire = out + (size_t)B_ * C_;   // second output region (also fs_ini accumulator)

  const size_t WS_X  = (size_t)B_ * D_ * sizeof(unsigned short);       // 4 MiB
  const size_t WS_WT = (size_t)R_ * C_ * D_ * sizeof(unsigned short);  // 8 MiB
  const size_t WS_PS = (size_t)R_ * D_ * 2 * sizeof(float);            // 256 KiB
  if (ws_size < WS_X + WS_WT + WS_PS) return;  // insufficient scratch -> visible failure

  unsigned short* xw  = (unsigned short*)d_ws;
  unsigned short* wtp = (unsigned short*)((char*)d_ws + WS_X);
  float*          ps  = (float*)((char*)d_ws + WS_X + WS_WT);

  // zero BOTH output regions: out accumulates gemm atomics, fire accumulates fs partials
  hipMemsetAsync(d_out, 0, (size_t)out_size * sizeof(float), stream);
  prep_x_kernel<<<dim3((B_ * D_ / 4) / 256), dim3(256), 0, stream>>>(x, xw);
  prep_w_kernel<<<dim3(R_ * 64), dim3(256), 0, stream>>>(W, wtp);
  prep_ps_kernel<<<dim3(R_ * D_ / 256), dim3(256), 0, stream>>>(proto, var, ps);
  fs_partial_kernel<<<dim3(B_ / 16, 8), dim3(256), 0, stream>>>(x, ps, fire);
  softmax_kernel<<<dim3(B_ / 4), dim3(256), 0, stream>>>(fire);
  gemm_kernel<<<dim3(512), dim3(256), 0, stream>>>(xw, wtp, fire, bias, out);
}

// Round 13
// 114.082 us; speedup vs baseline: 2.9553x; 1.0759x over previous
//
#include <hip/hip_runtime.h>
#include <hip/hip_bf16.h>
#include <cmath>

#define R_ 64
#define B_ 4096
#define D_ 512
#define C_ 128

typedef __attribute__((ext_vector_type(8))) short bf16x8;
typedef __attribute__((ext_vector_type(4))) float f32x4;

__device__ __forceinline__ unsigned short f2bf(float f) {
  union { float f; unsigned u; } x; x.f = f;
  unsigned r = (x.u + 0x7FFFu + ((x.u >> 16) & 1u)) >> 16;
  return (unsigned short)r;
}

// ---------------- prep: W[r][d][c] f32 -> W^T[r][c][d] bf16 ----------------
__global__ void prep_w_kernel(const float* __restrict__ W, unsigned short* __restrict__ wt) {
  __shared__ float t[32][33];
  int bx = blockIdx.x;
  int r = bx >> 6;
  int rem = bx & 63;
  int d0 = (rem >> 2) << 5;   // 16 d-tiles of 32
  int c0 = (rem & 3) << 5;    // 4 c-tiles of 32
  int tx = threadIdx.x & 31, ty = threadIdx.x >> 5;  // 32 x 8
  const float* Wr = W + (size_t)r * D_ * C_;
#pragma unroll
  for (int q = 0; q < 4; ++q) {
    int dl = q * 8 + ty;
    t[dl][tx] = Wr[(size_t)(d0 + dl) * C_ + c0 + tx];
  }
  __syncthreads();
  unsigned short* wtr = wt + (size_t)r * C_ * D_;
#pragma unroll
  for (int q = 0; q < 4; ++q) {
    int cl = q * 8 + ty;
    float v = t[tx][cl];                         // transposed read, pad-33 conflict-free
    wtr[(size_t)(c0 + cl) * D_ + d0 + tx] = f2bf(v);
  }
}

// ---------------- prep: (s, -p*s) per (rule, dim) ----------------
__global__ void prep_ps_kernel(const float* __restrict__ proto, const float* __restrict__ var,
                               float* __restrict__ ps) {
  int i = blockIdx.x * 256 + threadIdx.x;          // R*D elements
  float v = fminf(fmaxf(var[i], 1e-4f), 0.1f);
  float s = 1.2011224087864498f / v;
  float2 o; o.x = s; o.y = -proto[i] * s;
  reinterpret_cast<float2*>(ps)[i] = o;
}

// ---------------- antecedent partial + fused x->bf16 emission ----------------
// grid (B/16, 8). Each block covers x rows b0..b0+15, dims dq*64..+63 (disjoint
// coverage) -> also emits the bf16 copy of that x tile for the gemm (prep_x fused).
__global__ __launch_bounds__(256, 4) void fs_partial_kernel(
    const float* __restrict__ x, const float* __restrict__ ps,
    float* __restrict__ fire, unsigned short* __restrict__ xw) {
  __shared__ float x_s[16 * 68];
  __shared__ __align__(16) float ps_s[64 * 128];   // [rule][dim*2], XOR-swizzled granules
  const int tid = threadIdx.x;
  const int b0 = blockIdx.x * 16;
  const int dq = blockIdx.y;                       // dims dq*64 .. dq*64+63

  {  // stage x tile: 16 rows x 64 dims
    int row = tid >> 4, c4 = tid & 15;
    float4 v = *reinterpret_cast<const float4*>(&x[(size_t)(b0 + row) * D_ + dq * 64 + c4 * 4]);
    *reinterpret_cast<float4*>(&x_s[row * 68 + c4 * 4]) = v;
  }
#pragma unroll
  for (int k = 0; k < 8; ++k) {  // stage ps tile: 64 rules x 32 granules(16B), swizzled
    int g = tid + k * 256;
    int row = g >> 5, gi = g & 31;
    float4 v = *reinterpret_cast<const float4*>(&ps[(size_t)row * (D_ * 2) + dq * 128 + gi * 4]);
    int gs = gi ^ (row & 31);
    *reinterpret_cast<float4*>((char*)ps_s + row * 512 + (gs << 4)) = v;
  }
  __syncthreads();

  {  // fused prep_x: emit bf16 of this block's x tile (disjoint across grid)
    int row = tid >> 4, c0 = (tid & 15) * 4;
    const float* sp = &x_s[row * 68 + c0];
    ushort4 o;
    o.x = f2bf(sp[0]); o.y = f2bf(sp[1]); o.z = f2bf(sp[2]); o.w = f2bf(sp[3]);
    *reinterpret_cast<ushort4*>(&xw[(size_t)(b0 + row) * D_ + dq * 64 + c0]) = o;
  }

  const int tr = tid & 63;   // rule = lane
  const int tb = tid >> 6;   // wave -> 4 batch rows
  const int s31 = tr & 31;
  const char* pb = (const char*)ps_s + tr * 512;
  float facc[4] = {0.f, 0.f, 0.f, 0.f};

#pragma unroll
  for (int d4 = 0; d4 < 16; ++d4) {
    float4 psa = *reinterpret_cast<const float4*>(pb + ((((d4 * 2) ^ s31)) << 4));
    float4 psb = *reinterpret_cast<const float4*>(pb + ((((d4 * 2 + 1) ^ s31)) << 4));
#pragma unroll
    for (int i = 0; i < 4; ++i) {
      float4 xv = *reinterpret_cast<const float4*>(&x_s[(tb * 4 + i) * 68 + d4 * 4]);
      float u0 = fmaf(xv.x, psa.x, psa.y);
      float u1 = fmaf(xv.y, psa.z, psa.w);
      float u2 = fmaf(xv.z, psb.x, psb.y);
      float u3 = fmaf(xv.w, psb.z, psb.w);
      facc[i] += exp2f(-(u0 * u0)) + exp2f(-(u1 * u1)) +
                 exp2f(-(u2 * u2)) + exp2f(-(u3 * u3));
    }
  }
#pragma unroll
  for (int i = 0; i < 4; ++i)
    atomicAdd(&fire[(size_t)(b0 + tb * 4 + i) * R_ + tr], facc[i]);
}

// ---------------- softmax over rules, in place on fire buffer ----------------
__global__ void softmax_kernel(float* __restrict__ fire) {
  const int b = blockIdx.x * 4 + (threadIdx.x >> 6);
  const int r = threadIdx.x & 63;
  float v = fire[(size_t)b * R_ + r];
  float m = v;
#pragma unroll
  for (int off = 32; off; off >>= 1) m = fmaxf(m, __shfl_xor(m, off, 64));
  float e = exp2f((v - m) * 1.4426950408889634f);
  float s = e;
#pragma unroll
  for (int off = 32; off; off >>= 1) s += __shfl_xor(s, off, 64);
  fire[(size_t)b * R_ + r] = e / s;
}

// ---------------- fused rule-GEMM + relu + fire-weighted combine ----------------
// REG-STAGING variant: global_load_dwordx4 -> VGPR -> swizzled ds_write
// (replaces the global_load_lds DMA path — the single variable under test).
// BM=128, BN=C=128, BK=64, 4 rules/block. 8 waves (2x4), wave tile 64x32.
// Global source is LINEAR; swizzle lives on the LDS write + read sides.
__global__ __launch_bounds__(512, 4) void gemm_kernel(
    const unsigned short* __restrict__ xw, const unsigned short* __restrict__ wt,
    const float* __restrict__ fire, const float* __restrict__ bias,
    float* __restrict__ out) {
  __shared__ __align__(16) unsigned short x_s[2][128 * 64];   // 2 x 16 KB
  __shared__ __align__(16) unsigned short w_s[2][128 * 64];   // 2 x 16 KB
  __shared__ float fire_s[128 * 4];
  __shared__ float bias_s[4 * 128];

  const int tid = threadIdx.x;       // 0..511
  // XCD-aware decode (kept from R12; neutral)
  const int f = blockIdx.x;          // 0..511
  const int xcd = f & 7;
  const int idx = f >> 3;            // 0..63
  const int rg = 2 * xcd + (idx & 1);
  const int bm = idx >> 1;           // 0..31
  const int b0 = bm * 128;

  {
    int row = tid >> 2, g = tid & 3;
    fire_s[tid] = fire[(size_t)(b0 + row) * R_ + rg * 4 + g];
    bias_s[tid] = bias[rg * 4 * C_ + tid];
  }

  const int wid = tid >> 6, lane = tid & 63;
  const int wm = wid >> 2, wn = wid & 3;           // 2 x 4 wave grid, wave tile 64x32
  const int l16 = lane & 15, lhi = lane >> 4;

  // ds_read byte offsets (XOR-swizzled 16B granules within 128B rows)
  int offA[4][2], offB[2][2];
#pragma unroll
  for (int m = 0; m < 4; ++m) {
    int row = wm * 64 + m * 16 + l16;              // 0..127
#pragma unroll
    for (int ks = 0; ks < 2; ++ks)
      offA[m][ks] = row * 128 + (((ks * 4 + lhi) ^ (row & 7)) << 4);
  }
#pragma unroll
  for (int n = 0; n < 2; ++n) {
    int row = wn * 32 + n * 16 + l16;              // 0..127
#pragma unroll
    for (int ks = 0; ks < 2; ++ks)
      offB[n][ks] = row * 128 + (((ks * 4 + lhi) ^ (row & 7)) << 4);
  }

  // staging chunk maps: 1024 chunks each for A and B; 2 per thread each.
  // global offset LINEAR, LDS dest swizzled.
  int a_goff[2], a_ldst[2], b_goff[2], b_ldst[2];
#pragma unroll
  for (int q = 0; q < 2; ++q) {
    int ch = q * 512 + tid;
    int row = ch >> 3, g = ch & 7;
    a_goff[q] = row * D_ + g * 8;
    a_ldst[q] = row * 128 + ((g ^ (row & 7)) << 4);
    b_goff[q] = row * D_ + g * 8;
    b_ldst[q] = row * 128 + ((g ^ (row & 7)) << 4);
  }

  const unsigned short* xsrc = xw + (size_t)b0 * D_;
  const unsigned short* wbase = wt + (size_t)(rg * 4) * C_ * D_;

  float tot[4][2][4];
#pragma unroll
  for (int m = 0; m < 4; ++m)
#pragma unroll
    for (int n = 0; n < 2; ++n)
#pragma unroll
      for (int j = 0; j < 4; ++j) tot[m][n][j] = 0.f;

  f32x4 acc[4][2];

  // prologue: stage tile 0 via regs
  {
    uint4 la[2], lb[2];
#pragma unroll
    for (int q = 0; q < 2; ++q) {
      la[q] = *reinterpret_cast<const uint4*>(xsrc + a_goff[q]);
      lb[q] = *reinterpret_cast<const uint4*>(wbase + b_goff[q]);
    }
#pragma unroll
    for (int q = 0; q < 2; ++q) {
      *reinterpret_cast<uint4*>((char*)x_s[0] + a_ldst[q]) = la[q];
      *reinterpret_cast<uint4*>((char*)w_s[0] + b_ldst[q]) = lb[q];
    }
  }
  __syncthreads();

  int cur = 0;
  for (int s = 0; s < 32; ++s) {
    const int g = s >> 3, kk = s & 7;
    if (kk == 0) {
#pragma unroll
      for (int m = 0; m < 4; ++m)
#pragma unroll
        for (int n = 0; n < 2; ++n)
          acc[m][n] = f32x4{0.f, 0.f, 0.f, 0.f};
    }
    // issue next tile's global loads early (overlap with ds_read+MFMA below)
    uint4 la[2], lb[2];
    if (s + 1 < 32) {
      const int s1 = s + 1;
      const unsigned short* xs1 = xsrc + (s1 & 7) * 64;
      const unsigned short* ws1 = wbase + (size_t)(s1 >> 3) * C_ * D_ + (s1 & 7) * 64;
#pragma unroll
      for (int q = 0; q < 2; ++q) {
        la[q] = *reinterpret_cast<const uint4*>(xs1 + a_goff[q]);
        lb[q] = *reinterpret_cast<const uint4*>(ws1 + b_goff[q]);
      }
    }
    const char* xb = (const char*)x_s[cur];
    const char* wb = (const char*)w_s[cur];
#pragma unroll
    for (int ks = 0; ks < 2; ++ks) {
      bf16x8 av[4], bv[2];
#pragma unroll
      for (int m = 0; m < 4; ++m)
        av[m] = *reinterpret_cast<const bf16x8*>(xb + offA[m][ks]);
#pragma unroll
      for (int n = 0; n < 2; ++n)
        bv[n] = *reinterpret_cast<const bf16x8*>(wb + offB[n][ks]);
#pragma unroll
      for (int m = 0; m < 4; ++m)
#pragma unroll
        for (int n = 0; n < 2; ++n)
          acc[m][n] = __builtin_amdgcn_mfma_f32_16x16x32_bf16(av[m], bv[n], acc[m][n], 0, 0, 0);
    }
    if (kk == 7) {  // rule g finished: relu(+bias) * fire, accumulate
#pragma unroll
      for (int m = 0; m < 4; ++m)
#pragma unroll
        for (int n = 0; n < 2; ++n) {
          int col = wn * 32 + n * 16 + l16;
          float bi = bias_s[g * 128 + col];
#pragma unroll
          for (int j = 0; j < 4; ++j) {
            int rowl = wm * 64 + m * 16 + lhi * 4 + j;
            float v = acc[m][n][j] + bi;
            v = fmaxf(v, 0.f);
            tot[m][n][j] += v * fire_s[rowl * 4 + g];
          }
        }
    }
    if (s + 1 < 32) {
      // compiler inserts vmcnt waits on la/lb use; writes target buf^1 whose
      // readers all passed the previous barrier.
#pragma unroll
      for (int q = 0; q < 2; ++q) {
        *reinterpret_cast<uint4*>((char*)x_s[cur ^ 1] + a_ldst[q]) = la[q];
        *reinterpret_cast<uint4*>((char*)w_s[cur ^ 1] + b_ldst[q]) = lb[q];
      }
    }
    __syncthreads();
    cur ^= 1;
  }

#pragma unroll
  for (int m = 0; m < 4; ++m)
#pragma unroll
    for (int n = 0; n < 2; ++n) {
      int col = wn * 32 + n * 16 + l16;
#pragma unroll
      for (int j = 0; j < 4; ++j) {
        int rowl = wm * 64 + m * 16 + lhi * 4 + j;
        atomicAdd(&out[(size_t)(b0 + rowl) * C_ + col], tot[m][n][j]);
      }
    }
}

extern "C" void kernel_launch(void* const* d_in, const int* in_sizes, int n_in,
                              void* d_out, int out_size, void* d_ws, size_t ws_size,
                              hipStream_t stream) {
  const float* x     = (const float*)d_in[0];
  const float* proto = (const float*)d_in[1];
  const float* var   = (const float*)d_in[2];
  const float* W     = (const float*)d_in[3];
  const float* bias  = (const float*)d_in[4];
  float* out  = (float*)d_out;
  float* fire = out + (size_t)B_ * C_;   // second output region (also fs_ini accumulator)

  const size_t WS_X  = (size_t)B_ * D_ * sizeof(unsigned short);       // 4 MiB
  const size_t WS_WT = (size_t)R_ * C_ * D_ * sizeof(unsigned short);  // 8 MiB
  const size_t WS_PS = (size_t)R_ * D_ * 2 * sizeof(float);            // 256 KiB
  if (ws_size < WS_X + WS_WT + WS_PS) return;  // insufficient scratch -> visible failure

  unsigned short* xw  = (unsigned short*)d_ws;
  unsigned short* wtp = (unsigned short*)((char*)d_ws + WS_X);
  float*          ps  = (float*)((char*)d_ws + WS_X + WS_WT);

  // zero BOTH output regions: out accumulates gemm atomics, fire accumulates fs partials
  hipMemsetAsync(d_out, 0, (size_t)out_size * sizeof(float), stream);
  prep_w_kernel<<<dim3(R_ * 64), dim3(256), 0, stream>>>(W, wtp);
  prep_ps_kernel<<<dim3(R_ * D_ / 256), dim3(256), 0, stream>>>(proto, var, ps);
  fs_partial_kernel<<<dim3(B_ / 16, 8), dim3(256), 0, stream>>>(x, ps, fire, xw);
  softmax_kernel<<<dim3(B_ / 4), dim3(256), 0, stream>>>(fire);
  gemm_kernel<<<dim3(512), dim3(512), 0, stream>>>(xw, wtp, fire, bias, out);
}